// Round 10
// baseline (119.421 us; speedup 1.0000x reference)
//
#include <hip/hip_runtime.h>

// Problem constants (B=4, C=64, H=W=128, O=64, K=3, stride=1, pad=1, dil=1)
#define B_   4
#define C_   64
#define O_   64
#define H_   128
#define W_   128
#define HW_  (H_ * W_)
#define KK_  9
#define M_   18          // 2*KK offset channels

typedef short  short8  __attribute__((ext_vector_type(8)));
typedef float  floatx4 __attribute__((ext_vector_type(4)));
typedef unsigned short ushort4v __attribute__((ext_vector_type(4)));
typedef unsigned short ushort8v __attribute__((ext_vector_type(8)));

static __device__ __forceinline__ unsigned short f2bf(float f) {
    unsigned int u = __float_as_uint(f);
    u += 0x7FFFu + ((u >> 16) & 1u);     // round-to-nearest-even
    return (unsigned short)(u >> 16);
}
static __device__ __forceinline__ float bf2f(unsigned short s) {
    return __uint_as_float((unsigned int)s << 16);
}

// ---------------------------------------------------------------------------
// Prep (single launch) -- unchanged from round 8:
//  blocks [0,512):   x -> xT[b][g16][y][x][c16] bf16 (one corner x 4 ch = 8 B)
//  blocks [512,530): wtbf  = main-conv B-fragments in lane order
//                    [chunk*6+ks][otile][lane][8]  -> 1 KB contiguous per load
//  blocks [530,539): owtbf = offset-conv B-fragments in lane order
// ---------------------------------------------------------------------------
__global__ __launch_bounds__(256) void prep(
        const float* __restrict__ x, const float* __restrict__ w,
        const float* __restrict__ ow, unsigned short* __restrict__ xT,
        unsigned short* __restrict__ wtbf, unsigned short* __restrict__ owtbf) {
    const int blk = blockIdx.x;
    if (blk < 512) {
        __shared__ unsigned short T[128][72];   // [x][c], row padded to 72
        const int tid = threadIdx.x;
        const int y = blk & (H_ - 1);
        const int b = blk >> 7;
        const float* xby = x + (size_t)b * C_ * HW_ + y * W_;
        for (int i = tid; i < C_ * W_; i += 256) {
            const int c = i >> 7, xc = i & 127;
            T[xc][c] = f2bf(xby[(size_t)c * HW_ + xc]);
        }
        __syncthreads();
        unsigned short* dst = xT + (size_t)b * (4 * HW_ * 16) + y * (W_ * 16);
        for (int j = tid; j < 2048; j += 256) {
            const int g  = j >> 9;
            const int x8 = (j >> 2) & 127;
            const int c0 = (j & 3) * 4;
            const ushort4v pk = *(const ushort4v*)&T[x8][g * 16 + c0];
            *(ushort4v*)&dst[(size_t)g * (HW_ * 16) + x8 * 16 + c0] = pk;
        }
    } else if (blk < 530) {
        // wtbf: i = (cks*4 + ot)*64 + lane
        const int i = (blk - 512) * 256 + threadIdx.x;
        const int lane = i & 63, rest = i >> 6;
        const int ot = rest & 3, cks = rest >> 2;      // cks = chunk*6+ks
        const int chunk = cks / 6, ks = cks % 6;
        const int o = ot * 16 + (lane & 15);
        const int kbase = chunk * 192 + ks * 32 + (lane >> 4) * 8;
        ushort8v pk;
        #pragma unroll
        for (int j = 0; j < 8; ++j) {
            const int k = kbase + j;                   // k = tap*64 + c
            pk[j] = f2bf(w[o * 576 + (k & 63) * 9 + (k >> 6)]);
        }
        *(ushort8v*)&wtbf[(size_t)i * 8] = pk;
    } else {
        // owtbf: i = (tks*2 + tile)*64 + lane
        const int i = (blk - 530) * 256 + threadIdx.x;
        const int lane = i & 63, rest = i >> 6;
        const int tile = rest & 1, tks = rest >> 1;    // tks = tap*2+ks
        const int tap = tks >> 1, ks = tks & 1;
        const int m = tile * 16 + (lane & 15);
        const int cb = ks * 32 + (lane >> 4) * 8;
        ushort8v pk;
        #pragma unroll
        for (int j = 0; j < 8; ++j)
            pk[j] = (m < M_) ? f2bf(ow[m * 576 + (cb + j) * 9 + tap])
                             : (unsigned short)0;
        *(ushort8v*)&owtbf[(size_t)i * 8] = pk;
    }
}

// ---------------------------------------------------------------------------
// Fused deformable conv, K-SPLIT wave-private design for 32 waves/CU.
// Block = 32-px row segment, 4 waves: wave = (px-tile p = w&1, K-half h = w>>1).
//   A1: stage P[3][34][72] from xT (block-cooperative)          -> barrier
//   A2: each wave computes its tile's full-K offset conv via MFMA (36 MFMA,
//       redundant across halves -> zero cross-wave traffic)     -> barrier
//       offs (+ob folded) -> wave-private offs[w][18][16].
//   B (x3 chunks, NO barriers): wave samples ITS 32 channels for its 16 px
//       (geometry once per tap; 4-corner b64 loads, ~512B/instr window);
//       MFMAs its own vals k-columns against all 4 o-tiles (K-partial acc).
//   Tail: 2 barriers to exchange partial accs between K-halves; all 4 waves
//       finalize + store their o-half (coalesced via LDS transpose).
// Occupancy: LDS 16.9 KB, VGPR<=64 -> 8 blocks/CU = 32 waves/CU (HW max).
// XCD banding (blockIdx%8 = XCD): XCD x owns rows [16x,16x+16) -> xT slice
// L2-resident per XCD.
// ---------------------------------------------------------------------------
__global__ __launch_bounds__(256, 8) void dcn_fused(
        const unsigned short* __restrict__ xT,
        const unsigned short* __restrict__ owtbf, const float* __restrict__ ob,
        const unsigned short* __restrict__ wtbf, const float* __restrict__ bias,
        float* __restrict__ out) {
    __shared__ union {
        unsigned short P[3][34][72];                 // 14688 B (phase A)
        struct {
            unsigned short vals[32][192];            // 12288 B (phase B)
            float offs[4][M_][16];                   //  4608 B (wave-private)
        } bv;                                        // 16896 B
        struct {
            float ex[2][2][32][16];                  //  8192 B (acc exchange)
            float epw[2][2][32][17];                 //  8704 B (store staging)
        } ep;                                        // 16896 B
    } u;

    const int tid    = threadIdx.x;
    const int lane   = tid & 63;
    const int wslot  = __builtin_amdgcn_readfirstlane(tid >> 6);
    const int lane15 = lane & 15;
    const int quad   = lane >> 4;
    const int p      = wslot & 1;      // px-tile within the 32-px segment
    const int h      = wslot >> 1;     // K-half (channels [32h, 32h+32))

    // XCD-banded remap (g%8 = XCD): XCD x -> rows [16x,16x+16)
    const int g    = blockIdx.x;
    const int xcd  = g & 7;
    const int slot = g >> 3;                   // 0..255 per XCD
    const int ho   = xcd * 16 + (slot >> 4);
    const int rest = slot & 15;
    const int b    = rest >> 2;
    const int wo_base = (rest & 3) << 5;       // 32-px segment

    const unsigned short* xTb = xT + (size_t)b * (4 * HW_ * 16);

    // ---------------- Phase A1: stage 3 x-rows into P from xT ----------------
    // P[ky][r][c] = x[c][ho-1+ky][wo_base + r - 1],  r in [0,34)
    #pragma unroll
    for (int it = 0; it < 3; ++it) {
        const int t  = it * 4 + wslot;         // 0..11 = (ky, channel-group)
        const int ky = t >> 2, cgp = t & 3;
        const int y  = ho - 1 + ky;
        const bool yv = (unsigned)y < (unsigned)H_;
        const unsigned short* src = xTb + (size_t)cgp * (HW_ * 16) + y * (W_ * 16);
        const int r = lane;
        if (r < 34) {
            const int cx = wo_base + r - 1;
            ushort8v p0 = {0, 0, 0, 0, 0, 0, 0, 0};
            ushort8v p1 = {0, 0, 0, 0, 0, 0, 0, 0};
            if (yv && (unsigned)cx < (unsigned)W_) {
                p0 = *(const ushort8v*)&src[cx * 16];
                p1 = *(const ushort8v*)&src[cx * 16 + 8];
            }
            *(ushort8v*)&u.P[ky][r][cgp * 16]     = p0;
            *(ushort8v*)&u.P[ky][r][cgp * 16 + 8] = p1;
        }
    }
    __syncthreads();

    // ---------------- Phase A2: MFMA offset conv (full K, per wave) ---------
    floatx4 oa0 = (floatx4){0.f, 0.f, 0.f, 0.f};
    floatx4 oa1 = (floatx4){0.f, 0.f, 0.f, 0.f};
    #pragma unroll
    for (int ky = 0; ky < 3; ++ky) {
        #pragma unroll
        for (int kx = 0; kx < 3; ++kx) {
            const int tap = ky * 3 + kx;
            #pragma unroll
            for (int ks = 0; ks < 2; ++ks) {
                const int kk = ks * 32 + quad * 8;
                const short8 af =
                    *(const short8*)&u.P[ky][p * 16 + lane15 + kx][kk];
                const int fb = ((tap * 2 + ks) * 2) * 64 + lane;
                const short8 bf0 = *(const short8*)&owtbf[(size_t)fb * 8];
                const short8 bf1 = *(const short8*)&owtbf[(size_t)(fb + 64) * 8];
                oa0 = __builtin_amdgcn_mfma_f32_16x16x32_bf16(af, bf0, oa0, 0, 0, 0);
                oa1 = __builtin_amdgcn_mfma_f32_16x16x32_bf16(af, bf1, oa1, 0, 0, 0);
            }
        }
    }
    __syncthreads();   // all P reads done; vals/offs (aliasing P) now writable

    // Wave-private offsets (+ offset-conv bias folded in).
    {
        const float ob0 = ob[lane15];
        #pragma unroll
        for (int r = 0; r < 4; ++r) oa0[r] += ob0;
        *(floatx4*)&u.bv.offs[wslot][lane15][quad * 4] = oa0;
        if (lane15 < 2) {
            const float ob1 = ob[16 + lane15];
            #pragma unroll
            for (int r = 0; r < 4; ++r) oa1[r] += ob1;
            *(floatx4*)&u.bv.offs[wslot][16 + lane15][quad * 4] = oa1;
        }
    }

    // ---------------- Phase B: wave-private sample + MFMA (no barriers) -----
    const int cg4  = lane & 3;         // c16-subgroup within a 16-ch plane
    const int px16 = lane >> 2;        // pixel within the wave's tile
    const int row  = p * 16 + px16;    // vals row owned by this lane
    floatx4 acc[4];                    // K-partial, o-tiles 0..3
    #pragma unroll
    for (int t = 0; t < 4; ++t) acc[t] = (floatx4){0.f, 0.f, 0.f, 0.f};

    for (int chunk = 0; chunk < 3; ++chunk) {
        // --- B1: 3 taps x (geometry once -> 2 channel-groups of this half) --
        #pragma unroll
        for (int tl = 0; tl < 3; ++tl) {
            const int k  = chunk * 3 + tl;     // global tap 0..8
            const int ky = k / 3, kx = k % 3;
            const float offy = u.bv.offs[wslot][2 * k][px16];
            const float offx = u.bv.offs[wslot][2 * k + 1][px16];
            const float py  = (float)(ho - 1 + ky) + offy;
            const float pxx = (float)(wo_base - 1 + kx + p * 16 + px16) + offx;
            const float fy = floorf(py), fx = floorf(pxx);
            const int y0 = (int)fy, x0 = (int)fx;
            const int y1 = y0 + 1,  x1 = x0 + 1;
            const float wy1 = py - fy,  wy0 = 1.f - wy1;
            const float wx1 = pxx - fx, wx0 = 1.f - wx1;
            const bool y0v = (unsigned)y0 < (unsigned)H_;
            const bool y1v = (unsigned)y1 < (unsigned)H_;
            const bool x0v = (unsigned)x0 < (unsigned)W_;
            const bool x1v = (unsigned)x1 < (unsigned)W_;
            const float w00 = (y0v && x0v) ? wy0 * wx0 : 0.f;
            const float w01 = (y0v && x1v) ? wy0 * wx1 : 0.f;
            const float w10 = (y1v && x0v) ? wy1 * wx0 : 0.f;
            const float w11 = (y1v && x1v) ? wy1 * wx1 : 0.f;
            const int ry0 = min(max(y0, 0), H_ - 1);
            const int ry1 = min(max(y1, 0), H_ - 1);
            const int cx0 = min(max(x0, 0), W_ - 1);
            const int cx1 = min(max(x1, 0), W_ - 1);
            const int b00 = (ry0 * W_ + cx0) * 16 + cg4 * 4;
            const int b01 = (ry0 * W_ + cx1) * 16 + cg4 * 4;
            const int b10 = (ry1 * W_ + cx0) * 16 + cg4 * 4;
            const int b11 = (ry1 * W_ + cx1) * 16 + cg4 * 4;
            #pragma unroll
            for (int cgl = 0; cgl < 2; ++cgl) {
                const int cgrp = h * 2 + cgl;          // this wave's half
                const unsigned short* xp = xTb + (size_t)cgrp * (HW_ * 16);
                const ushort4v q00 = *(const ushort4v*)&xp[b00];
                const ushort4v q01 = *(const ushort4v*)&xp[b01];
                const ushort4v q10 = *(const ushort4v*)&xp[b10];
                const ushort4v q11 = *(const ushort4v*)&xp[b11];
                ushort4v pk;
                #pragma unroll
                for (int q = 0; q < 4; ++q) {
                    const float val = bf2f(q00[q]) * w00 + bf2f(q01[q]) * w01
                                    + bf2f(q10[q]) * w10 + bf2f(q11[q]) * w11;
                    pk[q] = f2bf(val);
                }
                // 16B chunk j = cgrp*2 + cg4>>1 (in [4h,4h+4)), ^ (row&7)
                const int cidx =
                    tl * 8 + (((cgrp << 1) + (cg4 >> 1)) ^ (px16 & 7));
                *(ushort4v*)&u.bv.vals[row][cidx * 8 + (cg4 & 1) * 4] = pk;
            }
        }

        // --- B2: MFMA own k-columns vs all 4 o-tiles (no barrier) ---
        #pragma unroll
        for (int sl = 0; sl < 3; ++sl) {
            const int s   = sl * 2 + h;                // 32-k step in [0,6)
            const int c16 = s * 4 + quad;
            const int ca  = c16 >> 3;
            const int cbr = (c16 & 7) ^ (lane15 & 7);
            const short8 afrag = *(const short8*)
                &u.bv.vals[p * 16 + lane15][(ca * 8 + cbr) * 8];
            #pragma unroll
            for (int t = 0; t < 4; ++t) {
                const short8 bfrag = *(const short8*)
                    &wtbf[(size_t)(((chunk * 6 + s) * 4 + t) * 64 + lane) * 8];
                acc[t] = __builtin_amdgcn_mfma_f32_16x16x32_bf16(
                             afrag, bfrag, acc[t], 0, 0, 0);
            }
        }
    }

    // ---------------- Tail: exchange K-half partials, finalize, store -------
    __syncthreads();                   // all vals reads done -> ex may alias
    #pragma unroll
    for (int tl = 0; tl < 2; ++tl) {   // write MY partials for the OTHER half
        const int t = 2 * (1 - h) + tl;
        *(floatx4*)&u.ep.ex[p][1 - h][tl * 16 + lane15][quad * 4] = acc[t];
    }
    __syncthreads();
    #pragma unroll
    for (int tl = 0; tl < 2; ++tl) {   // add partner's partials for MY half
        const int t = 2 * h + tl;
        const floatx4 part =
            *(const floatx4*)&u.ep.ex[p][h][tl * 16 + lane15][quad * 4];
        #pragma unroll
        for (int r = 0; r < 4; ++r) acc[t][r] += part[r];
        // stage for coalesced store: epw[o_local][px]
        #pragma unroll
        for (int r = 0; r < 4; ++r)
            u.ep.epw[p][h][tl * 16 + lane15][quad * 4 + r] = acc[t][r];
    }

    const int wo = wo_base + p * 16 + lane15;
    #pragma unroll
    for (int i = 0; i < 8; ++i) {
        const int o_local = i * 4 + quad;
        const int o = h * 32 + o_local;
        out[(size_t)(b * O_ + o) * HW_ + ho * W_ + wo] =
            u.ep.epw[p][h][o_local][lane15] + bias[o];
    }
}

// ---------------------------------------------------------------------------
extern "C" void kernel_launch(void* const* d_in, const int* in_sizes, int n_in,
                              void* d_out, int out_size, void* d_ws, size_t ws_size,
                              hipStream_t stream) {
    const float* x    = (const float*)d_in[0];  // [4,64,128,128]
    const float* ow   = (const float*)d_in[1];  // [18,64,3,3]
    const float* ob   = (const float*)d_in[2];  // [18]
    const float* w    = (const float*)d_in[3];  // [64,64,3,3]
    const float* bias = (const float*)d_in[4];  // [64]
    float* out = (float*)d_out;                 // [4,64,128,128]

    unsigned short* wtbf  = (unsigned short*)d_ws;      // 4608 frags  73728 B
    unsigned short* owtbf = wtbf + 4608 * 8;            // 2304 frags  36864 B
    unsigned short* xT    = owtbf + 2304 * 8;           // [4][4][HW][16] 8.39 MB

    prep<<<539, 256, 0, stream>>>(x, w, ow, xT, wtbf, owtbf);
    dcn_fused<<<B_ * H_ * (W_ / 32), 256, 0, stream>>>(xT, owtbf, ob, wtbf, bias, out);
}

// Round 11
// 110.693 us; speedup vs baseline: 1.0788x; 1.0788x over previous
//
#include <hip/hip_runtime.h>

// Problem constants (B=4, C=64, H=W=128, O=64, K=3, stride=1, pad=1, dil=1)
#define B_   4
#define C_   64
#define O_   64
#define H_   128
#define W_   128
#define HW_  (H_ * W_)
#define KK_  9
#define M_   18          // 2*KK offset channels

typedef short  short8  __attribute__((ext_vector_type(8)));
typedef float  floatx4 __attribute__((ext_vector_type(4)));
typedef unsigned short ushort4v __attribute__((ext_vector_type(4)));
typedef unsigned short ushort8v __attribute__((ext_vector_type(8)));

static __device__ __forceinline__ unsigned short f2bf(float f) {
    unsigned int u = __float_as_uint(f);
    u += 0x7FFFu + ((u >> 16) & 1u);     // round-to-nearest-even
    return (unsigned short)(u >> 16);
}
static __device__ __forceinline__ float bf2f(unsigned short s) {
    return __uint_as_float((unsigned int)s << 16);
}

// ---------------------------------------------------------------------------
// Prep (single launch) -- unchanged from round 8:
//  blocks [0,512):   x -> xT[b][g16][y][x][c16] bf16 (8 consecutive channels
//                    at one corner = ONE aligned b128 load)
//  blocks [512,530): wtbf  = main-conv B-fragments in lane order
//                    [chunk*6+ks][otile][lane][8]  -> 1 KB contiguous per load
//  blocks [530,539): owtbf = offset-conv B-fragments in lane order
// ---------------------------------------------------------------------------
__global__ __launch_bounds__(256) void prep(
        const float* __restrict__ x, const float* __restrict__ w,
        const float* __restrict__ ow, unsigned short* __restrict__ xT,
        unsigned short* __restrict__ wtbf, unsigned short* __restrict__ owtbf) {
    const int blk = blockIdx.x;
    if (blk < 512) {
        __shared__ unsigned short T[128][72];   // [x][c], row padded to 72
        const int tid = threadIdx.x;
        const int y = blk & (H_ - 1);
        const int b = blk >> 7;
        const float* xby = x + (size_t)b * C_ * HW_ + y * W_;
        for (int i = tid; i < C_ * W_; i += 256) {
            const int c = i >> 7, xc = i & 127;
            T[xc][c] = f2bf(xby[(size_t)c * HW_ + xc]);
        }
        __syncthreads();
        unsigned short* dst = xT + (size_t)b * (4 * HW_ * 16) + y * (W_ * 16);
        for (int j = tid; j < 2048; j += 256) {
            const int g  = j >> 9;
            const int x8 = (j >> 2) & 127;
            const int c0 = (j & 3) * 4;
            const ushort4v pk = *(const ushort4v*)&T[x8][g * 16 + c0];
            *(ushort4v*)&dst[(size_t)g * (HW_ * 16) + x8 * 16 + c0] = pk;
        }
    } else if (blk < 530) {
        // wtbf: i = (cks*4 + ot)*64 + lane
        const int i = (blk - 512) * 256 + threadIdx.x;
        const int lane = i & 63, rest = i >> 6;
        const int ot = rest & 3, cks = rest >> 2;      // cks = chunk*6+ks
        const int chunk = cks / 6, ks = cks % 6;
        const int o = ot * 16 + (lane & 15);
        const int kbase = chunk * 192 + ks * 32 + (lane >> 4) * 8;
        ushort8v pk;
        #pragma unroll
        for (int j = 0; j < 8; ++j) {
            const int k = kbase + j;                   // k = tap*64 + c
            pk[j] = f2bf(w[o * 576 + (k & 63) * 9 + (k >> 6)]);
        }
        *(ushort8v*)&wtbf[(size_t)i * 8] = pk;
    } else {
        // owtbf: i = (tks*2 + tile)*64 + lane
        const int i = (blk - 530) * 256 + threadIdx.x;
        const int lane = i & 63, rest = i >> 6;
        const int tile = rest & 1, tks = rest >> 1;    // tks = tap*2+ks
        const int tap = tks >> 1, ks = tks & 1;
        const int m = tile * 16 + (lane & 15);
        const int cb = ks * 32 + (lane >> 4) * 8;
        ushort8v pk;
        #pragma unroll
        for (int j = 0; j < 8; ++j)
            pk[j] = (m < M_) ? f2bf(ow[m * 576 + (cb + j) * 9 + tap])
                             : (unsigned short)0;
        *(ushort8v*)&owtbf[(size_t)i * 8] = pk;
    }
}

// ---------------------------------------------------------------------------
// Fused deformable conv, REGISTER-DIRECT A-fragments (no vals LDS at all).
// Block = 64-px row segment, 4 waves; wave w owns px-tile [16w,16w+16):
//   A1: stage P[3][66][72] from xT (block-cooperative)          -> barrier
//   A2: wave computes its tile's 18 offsets via MFMA; offs (+ob) to
//       wave-private offs[w][18][16] (separate LDS)             -> barrier
//       (barrier so epilogue's union writes can't race other waves' P reads)
//   B (x18 MFMA k-steps, ZERO barriers, ZERO LDS):
//       per step (chunk,ks): lane (px=lane15, quad) needs 8 consecutive
//       channels c0 = (ks&1)*32+quad*8 of tap chunk*3+(ks>>1) -> builds its
//       A-frag in registers from 4 corner b128 loads + fp32 bilinear + pack;
//       4 MFMAs vs lane-ordered wtbf fragments (1 KB bursts). Geometry
//       computed once per tap, shared by the 2 channel-halves.
//   Epilogue: wave-private staging in the (dead) P union -> coalesced stores.
// XCD banding (blockIdx%8 = XCD): XCD x owns rows [16x,16x+16) -> xT slice
// L2-resident per XCD.
// ---------------------------------------------------------------------------
__global__ __launch_bounds__(256, 4) void dcn_fused(
        const unsigned short* __restrict__ xT,
        const unsigned short* __restrict__ owtbf, const float* __restrict__ ob,
        const unsigned short* __restrict__ wtbf, const float* __restrict__ bias,
        float* __restrict__ out) {
    __shared__ union {
        unsigned short P[3][66][72];             // 28512 B (phase A)
        float ep[4][64][17];                     // 17408 B (epilogue, per wave)
    } u;
    __shared__ float offs[4][M_][16];            // 4608 B (wave-private)

    const int tid    = threadIdx.x;
    const int lane   = tid & 63;
    const int wslot  = __builtin_amdgcn_readfirstlane(tid >> 6);
    const int lane15 = lane & 15;
    const int quad   = lane >> 4;

    // XCD-banded remap (g%8 = XCD): XCD x -> rows [16x,16x+16), all b/half
    const int g    = blockIdx.x;
    const int xcd  = g & 7;
    const int slot = g >> 3;
    const int ho   = xcd * 16 + (slot >> 3);
    const int b    = (slot >> 1) & 3;
    const int wo_base = (slot & 1) << 6;

    const unsigned short* xTb = xT + (size_t)b * (4 * HW_ * 16);

    // ---------------- Phase A1: stage 3 x-rows into P from xT ----------------
    // P[ky][r][c] = x[c][ho-1+ky][wo_base + r - 1],  r in [0,66)
    #pragma unroll
    for (int it = 0; it < 3; ++it) {
        const int t  = it * 4 + wslot;         // 0..11 = (ky, channel-group)
        const int ky = t >> 2, cgp = t & 3;
        const int y  = ho - 1 + ky;
        const bool yv = (unsigned)y < (unsigned)H_;
        const unsigned short* src = xTb + (size_t)cgp * (HW_ * 16) + y * (W_ * 16);
        #pragma unroll
        for (int pass = 0; pass < 2; ++pass) {
            const int r = pass * 64 + lane;
            if (r < 66) {
                const int cx = wo_base + r - 1;
                ushort8v p0 = {0, 0, 0, 0, 0, 0, 0, 0};
                ushort8v p1 = {0, 0, 0, 0, 0, 0, 0, 0};
                if (yv && (unsigned)cx < (unsigned)W_) {
                    p0 = *(const ushort8v*)&src[cx * 16];
                    p1 = *(const ushort8v*)&src[cx * 16 + 8];
                }
                *(ushort8v*)&u.P[ky][r][cgp * 16]     = p0;
                *(ushort8v*)&u.P[ky][r][cgp * 16 + 8] = p1;
            }
        }
    }
    __syncthreads();

    // ---------------- Phase A2: MFMA offset conv ----------------
    floatx4 oa0 = (floatx4){0.f, 0.f, 0.f, 0.f};
    floatx4 oa1 = (floatx4){0.f, 0.f, 0.f, 0.f};
    {
        const int pxt = wslot;
        #pragma unroll
        for (int ky = 0; ky < 3; ++ky) {
            #pragma unroll
            for (int kx = 0; kx < 3; ++kx) {
                const int tap = ky * 3 + kx;
                #pragma unroll
                for (int ks = 0; ks < 2; ++ks) {
                    const int kk = ks * 32 + quad * 8;
                    const short8 af =
                        *(const short8*)&u.P[ky][pxt * 16 + lane15 + kx][kk];
                    const int fb = ((tap * 2 + ks) * 2) * 64 + lane;
                    const short8 bf0 = *(const short8*)&owtbf[(size_t)fb * 8];
                    const short8 bf1 =
                        *(const short8*)&owtbf[(size_t)(fb + 64) * 8];
                    oa0 = __builtin_amdgcn_mfma_f32_16x16x32_bf16(af, bf0, oa0, 0, 0, 0);
                    oa1 = __builtin_amdgcn_mfma_f32_16x16x32_bf16(af, bf1, oa1, 0, 0, 0);
                }
            }
        }
    }
    // Wave-private offsets (+ offset-conv bias folded in); separate LDS, no
    // barrier needed for own-wave consumption.
    {
        const float ob0 = ob[lane15];
        #pragma unroll
        for (int r = 0; r < 4; ++r) oa0[r] += ob0;
        *(floatx4*)&offs[wslot][lane15][quad * 4] = oa0;
        if (lane15 < 2) {
            const float ob1 = ob[16 + lane15];
            #pragma unroll
            for (int r = 0; r < 4; ++r) oa1[r] += ob1;
            *(floatx4*)&offs[wslot][16 + lane15][quad * 4] = oa1;
        }
    }
    __syncthreads();   // all P reads done -> epilogue may overwrite the union

    // ---------------- Phase B: register-direct A-frags + MFMA (no LDS) ------
    const int p   = wslot;              // wave's px-tile
    const int pxg = p * 16 + lane15;    // px within the 64-px segment
    floatx4 acc[4];                     // o-tiles 0..3
    #pragma unroll
    for (int t = 0; t < 4; ++t) acc[t] = (floatx4){0.f, 0.f, 0.f, 0.f};

    for (int chunk = 0; chunk < 3; ++chunk) {
        #pragma unroll
        for (int tl = 0; tl < 3; ++tl) {
            const int k  = chunk * 3 + tl;     // global tap 0..8
            const int ky = k / 3, kx = k % 3;
            // geometry once per tap (lane = its own pixel)
            const float offy = offs[wslot][2 * k][lane15];
            const float offx = offs[wslot][2 * k + 1][lane15];
            const float py  = (float)(ho - 1 + ky) + offy;
            const float pxx = (float)(wo_base - 1 + kx + pxg) + offx;
            const float fy = floorf(py), fx = floorf(pxx);
            const int y0 = (int)fy, x0 = (int)fx;
            const int y1 = y0 + 1,  x1 = x0 + 1;
            const float wy1 = py - fy,  wy0 = 1.f - wy1;
            const float wx1 = pxx - fx, wx0 = 1.f - wx1;
            const bool y0v = (unsigned)y0 < (unsigned)H_;
            const bool y1v = (unsigned)y1 < (unsigned)H_;
            const bool x0v = (unsigned)x0 < (unsigned)W_;
            const bool x1v = (unsigned)x1 < (unsigned)W_;
            const float w00 = (y0v && x0v) ? wy0 * wx0 : 0.f;
            const float w01 = (y0v && x1v) ? wy0 * wx1 : 0.f;
            const float w10 = (y1v && x0v) ? wy1 * wx0 : 0.f;
            const float w11 = (y1v && x1v) ? wy1 * wx1 : 0.f;
            const int ry0 = min(max(y0, 0), H_ - 1);
            const int ry1 = min(max(y1, 0), H_ - 1);
            const int cx0 = min(max(x0, 0), W_ - 1);
            const int cx1 = min(max(x1, 0), W_ - 1);
            const int a00 = (ry0 * W_ + cx0) * 16;
            const int a01 = (ry0 * W_ + cx1) * 16;
            const int a10 = (ry1 * W_ + cx0) * 16;
            const int a11 = (ry1 * W_ + cx1) * 16;
            #pragma unroll
            for (int chalf = 0; chalf < 2; ++chalf) {
                // this lane's channel octet for the MFMA k-layout
                const int c0 = chalf * 32 + quad * 8;
                const unsigned short* xp =
                    xTb + (size_t)(c0 >> 4) * (HW_ * 16) + (c0 & 8);
                const ushort8v q00 = *(const ushort8v*)&xp[a00];
                const ushort8v q01 = *(const ushort8v*)&xp[a01];
                const ushort8v q10 = *(const ushort8v*)&xp[a10];
                const ushort8v q11 = *(const ushort8v*)&xp[a11];
                ushort8v pk;
                #pragma unroll
                for (int j = 0; j < 8; ++j)
                    pk[j] = f2bf(bf2f(q00[j]) * w00 + bf2f(q01[j]) * w01
                               + bf2f(q10[j]) * w10 + bf2f(q11[j]) * w11);
                const short8 af = *(const short8*)&pk;
                const int cks = chunk * 6 + tl * 2 + chalf;
                #pragma unroll
                for (int t = 0; t < 4; ++t) {
                    const short8 bfrag = *(const short8*)
                        &wtbf[(size_t)((cks * 4 + t) * 64 + lane) * 8];
                    acc[t] = __builtin_amdgcn_mfma_f32_16x16x32_bf16(
                                 af, bfrag, acc[t], 0, 0, 0);
                }
            }
        }
    }

    // ---------------- Epilogue: wave-private staging, coalesced store -------
    // acc[t]: o = t*16+lane15 (col), px16 = quad*4+r (row).
    float* epw = &u.ep[wslot][0][0];
    #pragma unroll
    for (int t = 0; t < 4; ++t)
        #pragma unroll
        for (int r = 0; r < 4; ++r)
            epw[(t * 16 + lane15) * 17 + quad * 4 + r] = acc[t][r];

    const int wo = wo_base + p * 16 + lane15;
    #pragma unroll
    for (int i = 0; i < 16; ++i) {
        const int o = i * 4 + quad;
        out[(size_t)(b * O_ + o) * HW_ + ho * W_ + wo] =
            epw[o * 17 + lane15] + bias[o];
    }
}

// ---------------------------------------------------------------------------
extern "C" void kernel_launch(void* const* d_in, const int* in_sizes, int n_in,
                              void* d_out, int out_size, void* d_ws, size_t ws_size,
                              hipStream_t stream) {
    const float* x    = (const float*)d_in[0];  // [4,64,128,128]
    const float* ow   = (const float*)d_in[1];  // [18,64,3,3]
    const float* ob   = (const float*)d_in[2];  // [18]
    const float* w    = (const float*)d_in[3];  // [64,64,3,3]
    const float* bias = (const float*)d_in[4];  // [64]
    float* out = (float*)d_out;                 // [4,64,128,128]

    unsigned short* wtbf  = (unsigned short*)d_ws;      // 4608 frags  73728 B
    unsigned short* owtbf = wtbf + 4608 * 8;            // 2304 frags  36864 B
    unsigned short* xT    = owtbf + 2304 * 8;           // [4][4][HW][16] 8.39 MB

    prep<<<539, 256, 0, stream>>>(x, w, ow, xT, wtbf, owtbf);
    dcn_fused<<<B_ * H_ * (W_ / 64), 256, 0, stream>>>(xT, owtbf, ob, wtbf, bias, out);
}